// Round 14
// baseline (663.510 us; speedup 1.0000x reference)
//
#include <hip/hip_runtime.h>

// Problem constants (fixed by the reference).
#define T_LEN 4096
#define B_SZ  2
#define H_SZ  2048
#define NM    8            // N2 complex modes
#define BH    (B_SZ * H_SZ)

// Single-pass decomposition.
#define CHUNKS 64
#define LCH    (T_LEN / CHUNKS)          // 64 t-steps per chunk
#define HPB    256                       // h-columns per block (= blockDim)
#define NPAN   (H_SZ / HPB)              // 8 h-panels
#define NLANE  (B_SZ * NPAN)             // 16 independent scan lanes
#define NBLK   (CHUNKS * NLANE)          // 1024 blocks

// ---------------------------------------------------------------------------
// S4D single-pass chunked scan with decoupled lookback (CUB-style).
//   S_n(t) = w_n S_n(t-1) + x(t);  out = 2Re(sum_n Cd_n S_n) + D x.
//
// Round 18: the 3-kernel structure plateaued at ~152us (5 variants within
// noise). Structural costs removed here: x read twice from HBM, states
// double round-trip, 2 dispatch gaps. One kernel, no grid.sync (the r6
// spill trap was cg::sync's call ABI — this uses flags+atomics only):
//  - ticket (atomicAdd) assigns virtual block ids in increasing-chunk
//    order => a block only waits on earlier-claimed tickets (resident or
//    finished) => forward progress without cooperative launch.
//  - publish: data stores; __threadfence(); __syncthreads(); tid0
//    release-store flag (agent scope). consume: acquire-load flag, then
//    read. Handles cross-XCD L2 non-coherence.
//  - lookback walks predecessors' LOCAL sums (flag=1) — fully parallel,
//    no serial chain; INCLUSIVE (flag=2) short-circuits.
// ws: [ticket u32 @0 | flags int[NBLK] @64 | loc 16.8MB @8192 | inc 16.8MB].
// hipMemsetAsync zeroes first 8KB each iteration (graph-capture legal).
// ---------------------------------------------------------------------------

__global__ void __launch_bounds__(256, 4)
s4d_lookback(const float* __restrict__ x,
             const float* __restrict__ Dp,
             const float* __restrict__ log_dt,
             const float* __restrict__ Arl,
             const float* __restrict__ Aimp,
             const float* __restrict__ Crep,
             const float* __restrict__ Cimp,
             unsigned int* __restrict__ ticket,
             int* __restrict__ flags,
             float2* __restrict__ loc,
             float2* __restrict__ inc,
             float* __restrict__ out) {
    __shared__ unsigned int s_vbid;
    __shared__ int s_flag;
    const int tid = threadIdx.x;

    if (tid == 0) s_vbid = atomicAdd(ticket, 1u);
    __syncthreads();
    const int vb   = (int)s_vbid;
    const int c    = vb / NLANE;          // chunk index (ticket-ordered)
    const int lane = vb % NLANE;
    const int b    = lane / NPAN;
    const int h    = (lane % NPAN) * HPB + tid;

    // Per-mode recurrence weights w and w^LCH.
    const float dt = __expf(log_dt[h]);
    float wr[NM], wi[NM], wLr[NM], wLi[NM];
#pragma unroll
    for (int n = 0; n < NM; ++n) {
        float ar  = -__expf(Arl[h * NM + n]);
        float ai  = Aimp[h * NM + n];
        float er  = __expf(ar * dt);
        float ang = ai * dt;
        wr[n] = er * __cosf(ang);
        wi[n] = er * __sinf(ang);
        float erL  = __expf(ar * dt * (float)LCH);
        float angL = ai * dt * (float)LCH;
        wLr[n] = erL * __cosf(angL);
        wLi[n] = erL * __sinf(angL);
    }

    // ---- Phase A: chunk-local scan (zero initial state) -------------------
    float sr[NM], si[NM];
#pragma unroll
    for (int n = 0; n < NM; ++n) { sr[n] = 0.f; si[n] = 0.f; }

    const float* xp = x + (size_t)c * LCH * BH + b * H_SZ + h;
    {
        constexpr int BT = 8;
        float buf[BT], nxt[BT];
#pragma unroll
        for (int i = 0; i < BT; ++i) buf[i] = xp[(size_t)i * BH];
#pragma unroll
        for (int tb = 0; tb < LCH / BT; ++tb) {
            if (tb + 1 < LCH / BT) {
#pragma unroll
                for (int i = 0; i < BT; ++i)
                    nxt[i] = xp[(size_t)((tb + 1) * BT + i) * BH];
            }
#pragma unroll
            for (int i = 0; i < BT; ++i) {
                float xv = buf[i];
#pragma unroll
                for (int n = 0; n < NM; ++n) {
                    float nsr = fmaf(wr[n], sr[n], fmaf(-wi[n], si[n], xv));
                    float nsi = fmaf(wr[n], si[n], wi[n] * sr[n]);
                    sr[n] = nsr; si[n] = nsi;
                }
            }
#pragma unroll
            for (int i = 0; i < BT; ++i) buf[i] = nxt[i];
        }
    }

    // Publish local sum.
    const size_t ebase = (size_t)vb * NM * HPB + tid;
#pragma unroll
    for (int n = 0; n < NM; ++n)
        loc[ebase + (size_t)n * HPB] = make_float2(sr[n], si[n]);
    __threadfence();
    __syncthreads();

    // ---- Lookback: exclusive carry for this chunk -------------------------
    float cr[NM], ci[NM];
#pragma unroll
    for (int n = 0; n < NM; ++n) { cr[n] = 0.f; ci[n] = 0.f; }

    if (c == 0) {
        // inclusive == local
#pragma unroll
        for (int n = 0; n < NM; ++n)
            inc[ebase + (size_t)n * HPB] = make_float2(sr[n], si[n]);
        __threadfence();
        __syncthreads();
        if (tid == 0)
            __hip_atomic_store(&flags[vb], 2, __ATOMIC_RELEASE,
                               __HIP_MEMORY_SCOPE_AGENT);
    } else {
        if (tid == 0)
            __hip_atomic_store(&flags[vb], 1, __ATOMIC_RELEASE,
                               __HIP_MEMORY_SCOPE_AGENT);
        float pwr[NM], pwi[NM];
#pragma unroll
        for (int n = 0; n < NM; ++n) { pwr[n] = 1.f; pwi[n] = 0.f; }

        for (int j = c - 1; j >= 0; --j) {
            const int fidx = j * NLANE + lane;
            if (tid == 0) {
                int f;
                do {
                    f = __hip_atomic_load(&flags[fidx], __ATOMIC_ACQUIRE,
                                          __HIP_MEMORY_SCOPE_AGENT);
                    if (f == 0) __builtin_amdgcn_s_sleep(1);
                } while (f == 0);
                s_flag = f;
            }
            __syncthreads();
            const int f = s_flag;
            const float2* src = (f == 2 ? inc : loc) +
                                ((size_t)fidx * NM * HPB + tid);
#pragma unroll
            for (int n = 0; n < NM; ++n) {
                float2 v = src[(size_t)n * HPB];
                cr[n] = fmaf(pwr[n], v.x, fmaf(-pwi[n], v.y, cr[n]));
                ci[n] = fmaf(pwr[n], v.y, fmaf(pwi[n], v.x, ci[n]));
            }
            if (f == 2) break;           // uniform across block
#pragma unroll
            for (int n = 0; n < NM; ++n) {
                float t  = pwr[n] * wLr[n] - pwi[n] * wLi[n];
                pwi[n]   = pwr[n] * wLi[n] + pwi[n] * wLr[n];
                pwr[n]   = t;
            }
            __syncthreads();             // protect s_flag reuse next iter
        }

        // inclusive_c = local_c + w^L * carry; publish.
#pragma unroll
        for (int n = 0; n < NM; ++n) {
            float ir = sr[n] + (wLr[n] * cr[n] - wLi[n] * ci[n]);
            float ii = si[n] + (wLr[n] * ci[n] + wLi[n] * cr[n]);
            inc[ebase + (size_t)n * HPB] = make_float2(ir, ii);
        }
        __threadfence();
        __syncthreads();
        if (tid == 0)
            __hip_atomic_store(&flags[vb], 2, __ATOMIC_RELEASE,
                               __HIP_MEMORY_SCOPE_AGENT);
    }

    // ---- Phase C: rescan with carry-in, emit output -----------------------
    float cdr[NM], cdi[NM];
#pragma unroll
    for (int n = 0; n < NM; ++n) {
        float ar  = -__expf(Arl[h * NM + n]);
        float ai  = Aimp[h * NM + n];
        // Cd = (Cre + i*Cim) * (w - 1) / A  via conj(A)/|A|^2
        float inv = 1.0f / (ar * ar + ai * ai);
        float tr = ((wr[n] - 1.f) * ar + wi[n] * ai) * inv;
        float ti = (wi[n] * ar - (wr[n] - 1.f) * ai) * inv;
        float Cre = Crep[h * NM + n], Cim = Cimp[h * NM + n];
        cdr[n] = Cre * tr - Cim * ti;
        cdi[n] = Cre * ti + Cim * tr;
    }

#pragma unroll
    for (int n = 0; n < NM; ++n) { sr[n] = cr[n]; si[n] = ci[n]; }

    float Dv = Dp[h];
    float* op = out + (size_t)c * LCH * BH + b * H_SZ + h;
    {
        constexpr int BT = 8;
        float buf[BT], nxt[BT];
#pragma unroll
        for (int i = 0; i < BT; ++i) buf[i] = xp[(size_t)i * BH];
#pragma unroll
        for (int tb = 0; tb < LCH / BT; ++tb) {
            if (tb + 1 < LCH / BT) {
#pragma unroll
                for (int i = 0; i < BT; ++i)
                    nxt[i] = xp[(size_t)((tb + 1) * BT + i) * BH];
            }
#pragma unroll
            for (int i = 0; i < BT; ++i) {
                float xv = buf[i];
                float y = 0.f;
#pragma unroll
                for (int n = 0; n < NM; ++n) {
                    float nsr = fmaf(wr[n], sr[n], fmaf(-wi[n], si[n], xv));
                    float nsi = fmaf(wr[n], si[n], wi[n] * sr[n]);
                    sr[n] = nsr; si[n] = nsi;
                    y = fmaf(cdr[n], nsr, y);
                    y = fmaf(-cdi[n], nsi, y);
                }
                float ov = fmaf(Dv, xv, 2.0f * y);
                __builtin_nontemporal_store(ov, op + (size_t)(tb * BT + i) * BH);
            }
#pragma unroll
            for (int i = 0; i < BT; ++i) buf[i] = nxt[i];
        }
    }
}

// ---------------------------------------------------------------------------
// Fallback: proven 3-kernel path (152.1us, round-5 config).
// ---------------------------------------------------------------------------

template <int LC>
__global__ void __launch_bounds__(256, 4)
k1_chunk_end(const float* __restrict__ x, const float* __restrict__ log_dt,
             const float* __restrict__ Arl, const float* __restrict__ Aimp,
             float2* __restrict__ states) {
    int g = blockIdx.x * blockDim.x + threadIdx.x;
    int h = g % H_SZ;
    int b = (g / H_SZ) % B_SZ;
    int c = g / BH;
    float dt = __expf(log_dt[h]);
    float wr[NM], wi[NM];
#pragma unroll
    for (int n = 0; n < NM; ++n) {
        float ar = -__expf(Arl[h * NM + n]);
        float ai = Aimp[h * NM + n];
        float er = __expf(ar * dt);
        wr[n] = er * __cosf(ai * dt);
        wi[n] = er * __sinf(ai * dt);
    }
    float sr[NM], si[NM];
#pragma unroll
    for (int n = 0; n < NM; ++n) { sr[n] = 0.f; si[n] = 0.f; }
    const float* xp = x + (size_t)c * LC * BH + b * H_SZ + h;
    constexpr int BT = 8;
    float buf[BT], nxt[BT];
#pragma unroll
    for (int i = 0; i < BT; ++i) buf[i] = xp[(size_t)i * BH];
#pragma unroll
    for (int tb = 0; tb < LC / BT; ++tb) {
        if (tb + 1 < LC / BT) {
#pragma unroll
            for (int i = 0; i < BT; ++i)
                nxt[i] = xp[(size_t)((tb + 1) * BT + i) * BH];
        }
#pragma unroll
        for (int i = 0; i < BT; ++i) {
            float xv = buf[i];
#pragma unroll
            for (int n = 0; n < NM; ++n) {
                float nsr = fmaf(wr[n], sr[n], fmaf(-wi[n], si[n], xv));
                float nsi = fmaf(wr[n], si[n], wi[n] * sr[n]);
                sr[n] = nsr; si[n] = nsi;
            }
        }
#pragma unroll
        for (int i = 0; i < BT; ++i) buf[i] = nxt[i];
    }
    float2* st = states + (size_t)(c * B_SZ + b) * NM * H_SZ + h;
#pragma unroll
    for (int n = 0; n < NM; ++n) st[(size_t)n * H_SZ] = make_float2(sr[n], si[n]);
}

template <int CC, int LC>
__global__ void __launch_bounds__(128, 4)
k2_carry_scan(const float* __restrict__ log_dt, const float* __restrict__ Arl,
              const float* __restrict__ Aimp, float2* __restrict__ states) {
    int g = blockIdx.x * blockDim.x + threadIdx.x;
    int h = g % H_SZ;
    int n = (g / H_SZ) % NM;
    int b = g / (H_SZ * NM);
    float dt  = __expf(log_dt[h]);
    float Are = -__expf(Arl[h * NM + n]);
    float Aim = Aimp[h * NM + n];
    float er  = __expf(Are * dt * (float)LC);
    float ang = Aim * dt * (float)LC;
    float wr = er * __cosf(ang), wi = er * __sinf(ang);
    const size_t stride = (size_t)B_SZ * NM * H_SZ;
    float2* base = states + ((size_t)b * NM + n) * H_SZ + h;
    float cr = 0.f, ci = 0.f;
    constexpr int BT = 16;
    float2 buf[BT], nxt[BT];
#pragma unroll
    for (int i = 0; i < BT; ++i) buf[i] = base[(size_t)i * stride];
#pragma unroll
    for (int cb = 0; cb < CC / BT; ++cb) {
        if (cb + 1 < CC / BT) {
#pragma unroll
            for (int i = 0; i < BT; ++i)
                nxt[i] = base[(size_t)((cb + 1) * BT + i) * stride];
        }
#pragma unroll
        for (int i = 0; i < BT; ++i) {
            int c = cb * BT + i;
            base[(size_t)c * stride] = make_float2(cr, ci);
            float ncr = fmaf(wr, cr, fmaf(-wi, ci, buf[i].x));
            float nci = fmaf(wr, ci, fmaf(wi, cr, buf[i].y));
            cr = ncr; ci = nci;
        }
#pragma unroll
        for (int i = 0; i < BT; ++i) buf[i] = nxt[i];
    }
}

template <int LC>
__global__ void __launch_bounds__(256, 4)
k3_output(const float* __restrict__ x, const float* __restrict__ Dp,
          const float* __restrict__ log_dt, const float* __restrict__ Arl,
          const float* __restrict__ Aimp, const float* __restrict__ Crep,
          const float* __restrict__ Cimp, const float2* __restrict__ states,
          float* __restrict__ out) {
    int g = blockIdx.x * blockDim.x + threadIdx.x;
    int h = g % H_SZ;
    int b = (g / H_SZ) % B_SZ;
    int c = g / BH;
    float dt = __expf(log_dt[h]);
    float wr[NM], wi[NM], cdr[NM], cdi[NM];
#pragma unroll
    for (int n = 0; n < NM; ++n) {
        float ar = -__expf(Arl[h * NM + n]);
        float ai = Aimp[h * NM + n];
        float er = __expf(ar * dt);
        float wrn = er * __cosf(ai * dt);
        float win = er * __sinf(ai * dt);
        wr[n] = wrn; wi[n] = win;
        float inv = 1.0f / (ar * ar + ai * ai);
        float tr = ((wrn - 1.f) * ar + win * ai) * inv;
        float ti = (win * ar - (wrn - 1.f) * ai) * inv;
        float Cre = Crep[h * NM + n], Cim = Cimp[h * NM + n];
        cdr[n] = Cre * tr - Cim * ti;
        cdi[n] = Cre * ti + Cim * tr;
    }
    const float2* st = states + (size_t)(c * B_SZ + b) * NM * H_SZ + h;
    float sr[NM], si[NM];
#pragma unroll
    for (int n = 0; n < NM; ++n) {
        float2 v = st[(size_t)n * H_SZ];
        sr[n] = v.x; si[n] = v.y;
    }
    float Dv = Dp[h];
    const float* xp = x + (size_t)c * LC * BH + b * H_SZ + h;
    float* op = out + (size_t)c * LC * BH + b * H_SZ + h;
    constexpr int BT = 8;
    float buf[BT], nxt[BT];
#pragma unroll
    for (int i = 0; i < BT; ++i) buf[i] = xp[(size_t)i * BH];
#pragma unroll
    for (int tb = 0; tb < LC / BT; ++tb) {
        if (tb + 1 < LC / BT) {
#pragma unroll
            for (int i = 0; i < BT; ++i)
                nxt[i] = xp[(size_t)((tb + 1) * BT + i) * BH];
        }
#pragma unroll
        for (int i = 0; i < BT; ++i) {
            float xv = buf[i];
            float y = 0.f;
#pragma unroll
            for (int n = 0; n < NM; ++n) {
                float nsr = fmaf(wr[n], sr[n], fmaf(-wi[n], si[n], xv));
                float nsi = fmaf(wr[n], si[n], wi[n] * sr[n]);
                sr[n] = nsr; si[n] = nsi;
                y = fmaf(cdr[n], nsr, y);
                y = fmaf(-cdi[n], nsi, y);
            }
            float ov = fmaf(Dv, xv, 2.0f * y);
            __builtin_nontemporal_store(ov, op + (size_t)(tb * BT + i) * BH);
        }
#pragma unroll
        for (int i = 0; i < BT; ++i) buf[i] = nxt[i];
    }
}

extern "C" void kernel_launch(void* const* d_in, const int* in_sizes, int n_in,
                              void* d_out, int out_size, void* d_ws, size_t ws_size,
                              hipStream_t stream) {
    const float* x      = (const float*)d_in[0];
    const float* Dp     = (const float*)d_in[1];
    const float* log_dt = (const float*)d_in[2];
    const float* Arl    = (const float*)d_in[3];
    const float* Aimp   = (const float*)d_in[4];
    const float* Cre    = (const float*)d_in[5];
    const float* Cim    = (const float*)d_in[6];
    float* out = (float*)d_out;

    const size_t hdr   = 8192;                                   // ticket+flags
    const size_t esz   = (size_t)NBLK * NM * HPB * sizeof(float2); // 16.8 MB
    const size_t needL = hdr + 2 * esz;                          // ~33.6 MB

    if (ws_size >= needL) {
        char* base = (char*)d_ws;
        unsigned int* ticket = (unsigned int*)base;
        int*    flags = (int*)(base + 64);
        float2* loc   = (float2*)(base + hdr);
        float2* inc   = loc + (size_t)NBLK * NM * HPB;
        hipMemsetAsync(d_ws, 0, hdr, stream);
        s4d_lookback<<<NBLK, 256, 0, stream>>>(x, Dp, log_dt, Arl, Aimp,
                                               Cre, Cim, ticket, flags,
                                               loc, inc, out);
    } else {
        float2* states = (float2*)d_ws;
        constexpr int C = 32, LC = T_LEN / 32;    // 8.4 MB states
        int total1 = C * BH;
        k1_chunk_end<LC><<<total1 / 256, 256, 0, stream>>>(x, log_dt, Arl, Aimp, states);
        int total2 = BH * NM;
        k2_carry_scan<C, LC><<<total2 / 128, 128, 0, stream>>>(log_dt, Arl, Aimp, states);
        k3_output<LC><<<total1 / 256, 256, 0, stream>>>(x, Dp, log_dt, Arl, Aimp,
                                                        Cre, Cim, states, out);
    }
}

// Round 15
// 153.074 us; speedup vs baseline: 4.3346x; 4.3346x over previous
//
#include <hip/hip_runtime.h>

// Problem constants (fixed by the reference).
#define T_LEN 4096
#define B_SZ  2
#define H_SZ  2048
#define NM    8            // N2 complex modes
#define BH    (B_SZ * H_SZ)

// ---------------------------------------------------------------------------
// S4D via chunked linear recurrence (exact equivalent of the FFT conv):
//   S_n(t) = w_n * S_n(t-1) + x(t),  w_n = exp(dt*A_n)
//   out(t) = 2*Re( sum_n Cd_n * S_n(t) ) + D*x(t),  Cd = C*(w-1)/A
//
// FINAL REVERT to the best-measured configuration (152.1 us, round-5):
// scalar k1/k3 (BT=8, launch_bounds(256,4), 16 waves/CU), k2 at 256
// blocks x 128 thr BT=16, states [c][b][n][h], C=64.
//
// Structural post-mortems (why this shape is the local optimum):
//  - coop-kernel fusion: cg::grid.sync is a real call on ROCm; everything
//    live across it spills to scratch (VGPR=64, +110MB writes, 445us).
//  - decoupled lookback: per-tile state here is 16KB (256h x 8 modes),
//    so O(C^2) lookback reads = 528MB cross-XCD + 1008 spinning pollers
//    (663us, occupancy 45%, VALU 7%). Lookback needs few-byte states.
//  - h-pair vectorization: halved occupancy (16->8 waves/CU) outweighed
//    512B segments (156.4 vs 152.1).
//  - states transpose for k2 locality: null (155.3) — k2 stride never
//    was the bottleneck.
// The 3-kernel shape compresses the cross-chunk dependency into one
// 33.6MB round-trip (k2) and k3's x re-read is L3-hit; remaining waste
// is ~2 dispatch gaps, which no tested variant recovers.
// ---------------------------------------------------------------------------

template <int LC>
__global__ void __launch_bounds__(256, 4)
k1_chunk_end(const float* __restrict__ x,
             const float* __restrict__ log_dt,
             const float* __restrict__ Arl,
             const float* __restrict__ Aimp,
             float2* __restrict__ states) {
    int g = blockIdx.x * blockDim.x + threadIdx.x;   // [C * BH)
    int h = g % H_SZ;
    int b = (g / H_SZ) % B_SZ;
    int c = g / BH;

    float dt = __expf(log_dt[h]);
    float wr[NM], wi[NM];
#pragma unroll
    for (int n = 0; n < NM; ++n) {
        float ar  = -__expf(Arl[h * NM + n]);
        float ai  = Aimp[h * NM + n];
        float er  = __expf(ar * dt);
        float ang = ai * dt;
        wr[n] = er * __cosf(ang);
        wi[n] = er * __sinf(ang);
    }

    float sr[NM], si[NM];
#pragma unroll
    for (int n = 0; n < NM; ++n) { sr[n] = 0.f; si[n] = 0.f; }

    const float* xp = x + (size_t)c * LC * BH + b * H_SZ + h;

    constexpr int BT = 8;
    float buf[BT], nxt[BT];
#pragma unroll
    for (int i = 0; i < BT; ++i) buf[i] = xp[(size_t)i * BH];

#pragma unroll
    for (int tb = 0; tb < LC / BT; ++tb) {
        if (tb + 1 < LC / BT) {
#pragma unroll
            for (int i = 0; i < BT; ++i)
                nxt[i] = xp[(size_t)((tb + 1) * BT + i) * BH];
        }
#pragma unroll
        for (int i = 0; i < BT; ++i) {
            float xv = buf[i];
#pragma unroll
            for (int n = 0; n < NM; ++n) {
                float nsr = fmaf(wr[n], sr[n], fmaf(-wi[n], si[n], xv));
                float nsi = fmaf(wr[n], si[n], wi[n] * sr[n]);
                sr[n] = nsr; si[n] = nsi;
            }
        }
#pragma unroll
        for (int i = 0; i < BT; ++i) buf[i] = nxt[i];
    }

    // states[c][b][n][h]
    float2* st = states + (size_t)(c * B_SZ + b) * NM * H_SZ + h;
#pragma unroll
    for (int n = 0; n < NM; ++n) st[(size_t)n * H_SZ] = make_float2(sr[n], si[n]);
}

// 128-thread blocks: BH*NM = 32768 threads -> 256 blocks, one per CU.
// BT=16 prefetch covers cross-XCD L2/L3 latency on the 256KB-stride walk.
template <int CC, int LC>
__global__ void __launch_bounds__(128, 4)
k2_carry_scan(const float* __restrict__ log_dt,
              const float* __restrict__ Arl,
              const float* __restrict__ Aimp,
              float2* __restrict__ states) {
    int g = blockIdx.x * blockDim.x + threadIdx.x;   // [BH * NM), h fastest
    int h = g % H_SZ;
    int n = (g / H_SZ) % NM;
    int b = g / (H_SZ * NM);

    float dt  = __expf(log_dt[h]);
    float Are = -__expf(Arl[h * NM + n]);
    float Aim = Aimp[h * NM + n];
    // w^LC = exp(dt*A*LC)
    float er  = __expf(Are * dt * (float)LC);
    float ang = Aim * dt * (float)LC;
    float wr = er * __cosf(ang), wi = er * __sinf(ang);

    const size_t stride = (size_t)B_SZ * NM * H_SZ;  // chunk-to-chunk
    float2* base = states + ((size_t)b * NM + n) * H_SZ + h;

    float cr = 0.f, ci = 0.f;
    constexpr int BT = 16;
    float2 buf[BT], nxt[BT];
#pragma unroll
    for (int i = 0; i < BT; ++i) buf[i] = base[(size_t)i * stride];

#pragma unroll
    for (int cb = 0; cb < CC / BT; ++cb) {
        if (cb + 1 < CC / BT) {
#pragma unroll
            for (int i = 0; i < BT; ++i)
                nxt[i] = base[(size_t)((cb + 1) * BT + i) * stride];
        }
#pragma unroll
        for (int i = 0; i < BT; ++i) {
            int c = cb * BT + i;
            base[(size_t)c * stride] = make_float2(cr, ci);  // exclusive carry
            float ncr = fmaf(wr, cr, fmaf(-wi, ci, buf[i].x));
            float nci = fmaf(wr, ci, fmaf(wi, cr, buf[i].y));
            cr = ncr; ci = nci;
        }
#pragma unroll
        for (int i = 0; i < BT; ++i) buf[i] = nxt[i];
    }
}

template <int LC>
__global__ void __launch_bounds__(256, 4)
k3_output(const float* __restrict__ x,
          const float* __restrict__ Dp,
          const float* __restrict__ log_dt,
          const float* __restrict__ Arl,
          const float* __restrict__ Aimp,
          const float* __restrict__ Crep,
          const float* __restrict__ Cimp,
          const float2* __restrict__ states,
          float* __restrict__ out) {
    int g = blockIdx.x * blockDim.x + threadIdx.x;   // [C * BH)
    int h = g % H_SZ;
    int b = (g / H_SZ) % B_SZ;
    int c = g / BH;

    float dt = __expf(log_dt[h]);
    float wr[NM], wi[NM], cdr[NM], cdi[NM];
#pragma unroll
    for (int n = 0; n < NM; ++n) {
        float ar  = -__expf(Arl[h * NM + n]);
        float ai  = Aimp[h * NM + n];
        float er  = __expf(ar * dt);
        float ang = ai * dt;
        float wrn = er * __cosf(ang);
        float win = er * __sinf(ang);
        wr[n] = wrn; wi[n] = win;
        // Cd = (Cre + i*Cim) * (w - 1) / A  (divide via conj(A)/|A|^2)
        float inv = 1.0f / (ar * ar + ai * ai);
        float tr = ((wrn - 1.f) * ar + win * ai) * inv;
        float ti = (win * ar - (wrn - 1.f) * ai) * inv;
        float Cre = Crep[h * NM + n], Cim = Cimp[h * NM + n];
        cdr[n] = Cre * tr - Cim * ti;
        cdi[n] = Cre * ti + Cim * tr;
    }

    // carry-in: states[c][b][n][h]
    const float2* st = states + (size_t)(c * B_SZ + b) * NM * H_SZ + h;
    float sr[NM], si[NM];
#pragma unroll
    for (int n = 0; n < NM; ++n) {
        float2 v = st[(size_t)n * H_SZ];
        sr[n] = v.x; si[n] = v.y;
    }

    float Dv = Dp[h];
    const float* xp = x + (size_t)c * LC * BH + b * H_SZ + h;
    float* op = out + (size_t)c * LC * BH + b * H_SZ + h;

    constexpr int BT = 8;
    float buf[BT], nxt[BT];
#pragma unroll
    for (int i = 0; i < BT; ++i) buf[i] = xp[(size_t)i * BH];

#pragma unroll
    for (int tb = 0; tb < LC / BT; ++tb) {
        if (tb + 1 < LC / BT) {
#pragma unroll
            for (int i = 0; i < BT; ++i)
                nxt[i] = xp[(size_t)((tb + 1) * BT + i) * BH];
        }
#pragma unroll
        for (int i = 0; i < BT; ++i) {
            float xv = buf[i];
            float y = 0.f;
#pragma unroll
            for (int n = 0; n < NM; ++n) {
                float nsr = fmaf(wr[n], sr[n], fmaf(-wi[n], si[n], xv));
                float nsi = fmaf(wr[n], si[n], wi[n] * sr[n]);
                sr[n] = nsr; si[n] = nsi;
                y = fmaf(cdr[n], nsr, y);
                y = fmaf(-cdi[n], nsi, y);
            }
            float ov = fmaf(Dv, xv, 2.0f * y);
            __builtin_nontemporal_store(ov, op + (size_t)(tb * BT + i) * BH);
        }
#pragma unroll
        for (int i = 0; i < BT; ++i) buf[i] = nxt[i];
    }
}

extern "C" void kernel_launch(void* const* d_in, const int* in_sizes, int n_in,
                              void* d_out, int out_size, void* d_ws, size_t ws_size,
                              hipStream_t stream) {
    const float* x      = (const float*)d_in[0];
    const float* Dp     = (const float*)d_in[1];
    const float* log_dt = (const float*)d_in[2];
    const float* Arl    = (const float*)d_in[3];
    const float* Aimp   = (const float*)d_in[4];
    const float* Cre    = (const float*)d_in[5];
    const float* Cim    = (const float*)d_in[6];
    float* out = (float*)d_out;
    float2* states = (float2*)d_ws;

    const size_t need64 = (size_t)64 * BH * NM * sizeof(float2);   // 16.8 MB

    if (ws_size >= need64) {
        constexpr int C = 64, LC = T_LEN / 64;      // LC = 64
        int total1 = C * BH;                        // 262144 threads
        k1_chunk_end<LC><<<total1 / 256, 256, 0, stream>>>(x, log_dt, Arl, Aimp, states);
        int total2 = BH * NM;                       // 32768 threads, 128/block
        k2_carry_scan<C, LC><<<total2 / 128, 128, 0, stream>>>(log_dt, Arl, Aimp, states);
        k3_output<LC><<<total1 / 256, 256, 0, stream>>>(x, Dp, log_dt, Arl, Aimp,
                                                        Cre, Cim, states, out);
    } else {
        constexpr int C = 32, LC = T_LEN / 32;      // LC = 128 (8.4 MB states)
        int total1 = C * BH;
        k1_chunk_end<LC><<<total1 / 256, 256, 0, stream>>>(x, log_dt, Arl, Aimp, states);
        int total2 = BH * NM;
        k2_carry_scan<C, LC><<<total2 / 128, 128, 0, stream>>>(log_dt, Arl, Aimp, states);
        k3_output<LC><<<total1 / 256, 256, 0, stream>>>(x, Dp, log_dt, Arl, Aimp,
                                                        Cre, Cim, states, out);
    }
}